// Round 1
// 584.169 us; speedup vs baseline: 1.1130x; 1.1130x over previous
//
#include <hip/hip_runtime.h>
#include <cstdint>
#include <cstddef>

// TrimodalCrossAttention: seq_len=1 => softmax==1 => attention i reduces to
//   att_i(kv) = kv @ (Wo_i@Wv_i)^T + (Wo_i@bv_i + bo_i)
// Everything folds into: out = relu([g|d|c] @ A + bias_h) @ W2^T + b2
// with A [768,512] built from W1 and Wf_i = Wo_i@Wv_i.

typedef __attribute__((ext_vector_type(8))) short short8;
typedef __attribute__((ext_vector_type(4))) float float4v;

__device__ __forceinline__ unsigned short f2bf(float f) {
  union { float f; unsigned u; } v; v.f = f;
  unsigned r = v.u + 0x7FFFu + ((v.u >> 16) & 1u);   // round-to-nearest-even
  return (unsigned short)(r >> 16);
}

// ---------------- P1: fused {Wf = Wo@Wv} and {bfs} ---------------------------
// blocks 0..1535: Wf[i] = Wo[i]@Wv[i] (6x 256x256x256 fp32, 4-way acc split)
// blocks 1536..2303: bfs[p][m] = bo sums + Wo rows . bv (parallel, coalesced)
__global__ __launch_bounds__(256) void k_prep1(const float* __restrict__ Wo,
                                               const float* __restrict__ Wv,
                                               const float* __restrict__ bv,
                                               const float* __restrict__ bo,
                                               float* __restrict__ Wf,
                                               float* __restrict__ bfs) {
  __shared__ float red[256];
  int b = blockIdx.x;
  if (b < 1536) {
    int i = b >> 8, m = b & 255;
    int n = threadIdx.x;
    const float* wo = Wo + i * 65536 + m * 256;   // row m (uniform -> s_load)
    const float* wv = Wv + i * 65536 + n;         // column n (coalesced)
    float a0 = 0.f, a1 = 0.f, a2 = 0.f, a3 = 0.f; // break the dep chain
#pragma unroll 4
    for (int k = 0; k < 256; k += 4) {
      a0 += wo[k]     * wv[k * 256];
      a1 += wo[k + 1] * wv[(k + 1) * 256];
      a2 += wo[k + 2] * wv[(k + 2) * 256];
      a3 += wo[k + 3] * wv[(k + 3) * 256];
    }
    Wf[i * 65536 + m * 256 + n] = (a0 + a1) + (a2 + a3);
  } else {
    int bb = b - 1536;              // 0..767 : p*256 + m
    int p = bb >> 8, m = bb & 255;
    int t = threadIdx.x;
    int a = 2 * p, b2i = 2 * p + 1;
    float v = Wo[a * 65536 + m * 256 + t] * bv[a * 256 + t]
            + Wo[b2i * 65536 + m * 256 + t] * bv[b2i * 256 + t];
    red[t] = v; __syncthreads();
    for (int s = 128; s > 0; s >>= 1) { if (t < s) red[t] += red[t + s]; __syncthreads(); }
    if (t == 0) bfs[p * 256 + m] = red[0] + bo[a * 256 + m] + bo[b2i * 256 + m];
  }
}

// ---------------- P2: fused {A fold -> swizzled bf16}, {bias_h}, {W2 pack} ---
__global__ __launch_bounds__(256) void k_prep2(const float* __restrict__ W1,
                                               const float* __restrict__ b1,
                                               const float* __restrict__ Wf,
                                               const float* __restrict__ bfs,
                                               const float* __restrict__ W2,
                                               unsigned short* __restrict__ ATS,
                                               float* __restrict__ bias_h,
                                               unsigned short* __restrict__ W2p) {
  __shared__ float red[256];
  int b = blockIdx.x;
  if (b < 1536) {
    // fold A[k][n], write XOR-swizzled bf16 (layout matches main b-frag reads)
    int n = b & 511, p = b >> 9;     // p: 0=g,1=d,2=c  (k-part)
    int kk = threadIdx.x;
    int fA, oA, fB, oB;
    if (p == 0)      { fA = 2; oA = 256; fB = 4; oB = 512; }   // dg, cg
    else if (p == 1) { fA = 0; oA = 0;   fB = 5; oB = 512; }   // gd, cd
    else             { fA = 1; oA = 0;   fB = 3; oB = 256; }   // gc, dc
    const float* w1n = W1 + n * 768;
    const float* wfa = Wf + fA * 65536 + kk;
    const float* wfb = Wf + fB * 65536 + kk;
    float v0 = w1n[p * 256 + kk], v1 = 0.f, v2 = 0.f, v3 = 0.f;  // 4 chains
#pragma unroll 4
    for (int j = 0; j < 256; j += 2) {
      v0 += w1n[oA + j]     * wfa[j * 256];
      v1 += w1n[oA + j + 1] * wfa[(j + 1) * 256];
      v2 += w1n[oB + j]     * wfb[j * 256];
      v3 += w1n[oB + j + 1] * wfb[(j + 1) * 256];
    }
    float val = (v0 + v1) + (v2 + v3);
    int k = p * 256 + kk;
    int t = k >> 5, kq = (k >> 3) & 3, j8 = k & 7;
    int unit = n * 4 + (kq ^ (n & 3));
    ATS[t * 16384 + unit * 8 + j8] = f2bf(val);
  } else if (b < 2048) {
    // bias_h[n] = b1[n] + sum_k W1[n][k]*bfs[k]
    int n = b - 1536;
    int kk = threadIdx.x;
    const float* w1n = W1 + n * 768;
    float v = w1n[kk] * bfs[kk] + w1n[256 + kk] * bfs[256 + kk] +
              w1n[512 + kk] * bfs[512 + kk];
    red[kk] = v; __syncthreads();
    for (int s = 128; s > 0; s >>= 1) { if (kk < s) red[kk] += red[kk + s]; __syncthreads(); }
    if (kk == 0) bias_h[n] = red[0] + b1[n];
  } else {
    // W2 -> bf16, chunk-permuted for stage-2
    int id = (b - 2048) * 256 + threadIdx.x;       // 0..131071
    int cpos = id >> 14;
    int n = (id >> 6) & 255;
    int kp = id & 63;
    int t = kp >> 4, ci = kp & 15;
    W2p[id] = f2bf(W2[n * 512 + (cpos + 8 * t) * 16 + ci]);
  }
}

// ---------------- Main fused kernel -----------------------------------------
// Block: 128 rows x full N=512 hidden, 512 threads (8 waves), 1 block/CU.
// Stage 1: PIPELINED — prefetch tile kt+1 (X->regs, A->ats[dbuf]) while
//          computing tile kt; counted vmcnt(6) (never 0 in steady state) so
//          next-tile loads stay in flight across the barriers.
// Stage 2: out = relu(hidden) @ W2p + b2, chunked hidden exchange via LDS.
__global__ __launch_bounds__(512, 2) void k_main(
    const float* __restrict__ G, const float* __restrict__ D,
    const float* __restrict__ C, const unsigned short* __restrict__ ATS,
    const float* __restrict__ bias_h, const unsigned short* __restrict__ W2p,
    const float* __restrict__ b2, float* __restrict__ Out) {
  __shared__ unsigned short ats[2][16384];  // 64 KB double-buffered A tile
  __shared__ unsigned short xt[128][40];    // 10 KB X tile bf16 (single buf:
                                            // write is barrier-separated from prev reads)
  __shared__ unsigned short hid[128][72];   // 18 KB hidden chunk

  const int tid = threadIdx.x;
  const int lane = tid & 63, wave = tid >> 6;
  const int l15 = lane & 15, lq = lane >> 4;
  const int m0 = blockIdx.x * 128;
  const int wm = wave >> 2, wn = wave & 3;  // stage-1 wave tile: rows wm*64, cols wn*128

  float4v acc1[4][8];
#pragma unroll
  for (int j = 0; j < 8; ++j) {
    float bh = bias_h[wn * 128 + j * 16 + l15];
#pragma unroll
    for (int i = 0; i < 4; ++i) acc1[i][j] = (float4v){bh, bh, bh, bh};
  }

  const int xrow = tid >> 2, xseg = tid & 3;
  const int xoff = (m0 + xrow) * 256 + xseg * 8;   // 32-bit voffset, SGPR base

  float4v f0, f1, g0, g1;

#define ISSUE_X(kt1, ra, rb) do {                                           \
    int kt_ = (kt1);                                                        \
    const float* xb_ = (kt_ < 8) ? G : (kt_ < 16) ? D : C;                  \
    const float* xp_ = xb_ + xoff + (kt_ & 7) * 32;                         \
    ra = *(const float4v*)xp_;                                              \
    rb = *(const float4v*)(xp_ + 4);                                        \
  } while (0)

#define ISSUE_A(kt1, buf) do {                                              \
    const char* gsrc_ = (const char*)ATS + (size_t)(kt1) * 32768;           \
    char* ldst_ = (char*)&ats[buf][0];                                      \
    _Pragma("unroll")                                                       \
    for (int it_ = 0; it_ < 4; ++it_)                                       \
      __builtin_amdgcn_global_load_lds(                                     \
          (const __attribute__((address_space(1))) unsigned int*)(gsrc_ + it_ * 8192 + tid * 16), \
          (__attribute__((address_space(3))) unsigned int*)(ldst_ + it_ * 8192 + tid * 16), \
          16, 0, 0);                                                        \
  } while (0)

  // Per-thread VMEM issue order: X(kt)[2], A(kt)[4], X(kt+1)[2], A(kt+1)[4].
  // vmcnt(6) before the barrier => X(kt),A(kt) complete, next tile in flight.
#define BODY(kt_, buf, fa, fb, ga, gb, PREF) do {                           \
    if (PREF) { ISSUE_X((kt_) + 1, ga, gb); ISSUE_A((kt_) + 1, (buf) ^ 1); } \
    short8 xv_;                                                             \
    xv_[0] = f2bf(fa[0]); xv_[1] = f2bf(fa[1]);                             \
    xv_[2] = f2bf(fa[2]); xv_[3] = f2bf(fa[3]);                             \
    xv_[4] = f2bf(fb[0]); xv_[5] = f2bf(fb[1]);                             \
    xv_[6] = f2bf(fb[2]); xv_[7] = f2bf(fb[3]);                             \
    *(short8*)&xt[xrow][xseg * 8] = xv_;                                    \
    if (PREF) asm volatile("s_waitcnt vmcnt(6) lgkmcnt(0)" ::: "memory");   \
    else      asm volatile("s_waitcnt vmcnt(0) lgkmcnt(0)" ::: "memory");   \
    __builtin_amdgcn_s_barrier();                                           \
    __builtin_amdgcn_sched_barrier(0);                                      \
    short8 a_[4];                                                           \
    _Pragma("unroll")                                                       \
    for (int i_ = 0; i_ < 4; ++i_)                                          \
      a_[i_] = *(const short8*)&xt[wm * 64 + i_ * 16 + l15][lq * 8];        \
    _Pragma("unroll")                                                       \
    for (int j_ = 0; j_ < 8; ++j_) {                                        \
      int n_ = wn * 128 + j_ * 16 + l15;                                    \
      int unit_ = n_ * 4 + (lq ^ (n_ & 3));                                 \
      short8 bf_ = *(const short8*)&ats[buf][unit_ * 8];                    \
      _Pragma("unroll")                                                     \
      for (int i_ = 0; i_ < 4; ++i_)                                        \
        acc1[i_][j_] = __builtin_amdgcn_mfma_f32_16x16x32_bf16(a_[i_], bf_, acc1[i_][j_], 0, 0, 0); \
    }                                                                       \
    __builtin_amdgcn_sched_barrier(0);                                      \
    __builtin_amdgcn_s_barrier();                                           \
  } while (0)

  // prologue: tile 0 in flight before the loop
  ISSUE_X(0, f0, f1);
  ISSUE_A(0, 0);

  for (int kp = 0; kp < 11; ++kp) {
    BODY(2 * kp,     0, f0, f1, g0, g1, 1);
    BODY(2 * kp + 1, 1, g0, g1, f0, f1, 1);
  }
  BODY(22, 0, f0, f1, g0, g1, 1);
  BODY(23, 1, g0, g1, f0, f1, 0);

#undef BODY
#undef ISSUE_A
#undef ISSUE_X

  // ---- stage 2: out[128][256] += relu(hidden) @ W2 ----
  const int om = wave >> 2, on = wave & 3;  // out wave tile: rows om*64, cols on*64
  float4v acc2[4][4];
#pragma unroll
  for (int j = 0; j < 4; ++j) {
    float bb = b2[on * 64 + j * 16 + l15];
#pragma unroll
    for (int i = 0; i < 4; ++i) acc2[i][j] = (float4v){bb, bb, bb, bb};
  }

#pragma unroll
  for (int cpos = 0; cpos < 8; ++cpos) {
    // every wave writes its local n-tile j==cpos (global tile cpos+8*wn) -> chunk col wn*16
#pragma unroll
    for (int i = 0; i < 4; ++i) {
#pragma unroll
      for (int r = 0; r < 4; ++r) {
        float v = acc1[i][cpos][r];
        v = v > 0.f ? v : 0.f;                      // relu
        hid[wm * 64 + i * 16 + lq * 4 + r][wn * 16 + l15] = f2bf(v);
      }
    }
    asm volatile("s_waitcnt lgkmcnt(0)" ::: "memory");
    __builtin_amdgcn_s_barrier();
    __builtin_amdgcn_sched_barrier(0);
#pragma unroll
    for (int ks = 0; ks < 2; ++ks) {
      short8 a2[4];
#pragma unroll
      for (int i = 0; i < 4; ++i)
        a2[i] = *(const short8*)&hid[om * 64 + i * 16 + l15][ks * 32 + lq * 8];
#pragma unroll
      for (int j = 0; j < 4; ++j) {
        int n = on * 64 + j * 16 + l15;
        const unsigned short* bp = W2p + ((size_t)(cpos * 256 + n) * 64 + ks * 32 + lq * 8);
        short8 bfrag = *(const short8*)bp;
#pragma unroll
        for (int i = 0; i < 4; ++i)
          acc2[i][j] = __builtin_amdgcn_mfma_f32_16x16x32_bf16(a2[i], bfrag, acc2[i][j], 0, 0, 0);
      }
    }
    __builtin_amdgcn_sched_barrier(0);
    __builtin_amdgcn_s_barrier();
  }

  // epilogue: fp32 stores, 64B row segments per 16-lane group
#pragma unroll
  for (int i = 0; i < 4; ++i) {
#pragma unroll
    for (int r = 0; r < 4; ++r) {
      int row = m0 + om * 64 + i * 16 + lq * 4 + r;
      float* op = Out + (size_t)row * 256 + on * 64 + l15;
#pragma unroll
      for (int j = 0; j < 4; ++j) op[j * 16] = acc2[i][j][r];
    }
  }
}

// ---------------- launcher ---------------------------------------------------
extern "C" void kernel_launch(void* const* d_in, const int* in_sizes, int n_in,
                              void* d_out, int out_size, void* d_ws, size_t ws_size,
                              hipStream_t stream) {
  const float* G  = (const float*)d_in[0];
  const float* D  = (const float*)d_in[1];
  const float* C  = (const float*)d_in[2];
  // d_in[3]=Wq, d_in[4]=Wk unused: softmax over 1 key == 1 identically
  const float* Wv = (const float*)d_in[5];
  // d_in[6]=bq, d_in[7]=bk unused
  const float* bv = (const float*)d_in[8];
  const float* Wo = (const float*)d_in[9];
  const float* bo = (const float*)d_in[10];
  const float* W1 = (const float*)d_in[11];
  const float* b1 = (const float*)d_in[12];
  const float* W2 = (const float*)d_in[13];
  const float* b2 = (const float*)d_in[14];

  char* ws = (char*)d_ws;
  float* Wf           = (float*)(ws);                       // 1,572,864 B
  float* bfs          = (float*)(ws + 1572864);             //     3,072 B
  float* bias_h       = (float*)(ws + 1575936);             //     2,048 B
  unsigned short* ATS = (unsigned short*)(ws + 1577984);    //   786,432 B
  unsigned short* W2p = (unsigned short*)(ws + 2364416);    //   262,144 B  (~2.6 MB total)
  float* Out = (float*)d_out;

  hipLaunchKernelGGL(k_prep1, dim3(2304), dim3(256), 0, stream, Wo, Wv, bv, bo, Wf, bfs);
  hipLaunchKernelGGL(k_prep2, dim3(2560), dim3(256), 0, stream, W1, b1, Wf, bfs, W2, ATS, bias_h, W2p);
  hipLaunchKernelGGL(k_main,  dim3(1024), dim3(512), 0, stream, G, D, C, ATS, bias_h, W2p, b2, Out);
}